// Round 10
// baseline (213.070 us; speedup 1.0000x reference)
//
#include <hip/hip_runtime.h>
#include <hip/hip_bf16.h>

#define N_NODES 50000
#define N_EDGES 800000
#define F_IN    128
#define HC      128      // H*C
#define NR      8        // node ranges (XCD-pinned: fill block bid%8 == r)
#define RSZ     6250     // nodes per range
#define NCH     16       // edge chunks
#define CHSZ    50000    // edges per chunk
#define NP      50048    // padded node stride for part_t[c][n]

typedef __attribute__((ext_vector_type(8))) short bf16x8;
typedef __attribute__((ext_vector_type(4))) float f32x4;

__device__ __forceinline__ float bf2f(unsigned int u16) {
    return __uint_as_float(u16 << 16);
}
__device__ __forceinline__ unsigned int f2bf(float f) {
    unsigned int u = __float_as_uint(f);
    return (u + 0x7fffu + ((u >> 16) & 1u)) >> 16;   // RNE
}

// ---------------------------------------------------------------------------
// K_hist: blocks 0..127 = LDS sub-histogram for (range r=bid&7, chunk
// c=bid>>3); partials to part_t[c*NP + node] (coalesced transposed layout).
// Blocks 128..143: pack [Wg|Ws] -> Bfrag (MFMA-B fragment-major bf16).
// No global atomics anywhere in the CSR pipeline.
// ---------------------------------------------------------------------------
__global__ __launch_bounds__(256) void k_hist(
    const int* __restrict__ dst,
    const float* __restrict__ Wg, const float* __restrict__ Ws,
    unsigned short* __restrict__ Bfrag, int* __restrict__ part)
{
    const int bid = blockIdx.x;
    const int tid = threadIdx.x;
    if (bid < 128) {
        __shared__ int hist[RSZ];
        const int r = bid & 7, c = bid >> 3;
        const int nb = r * RSZ;
        for (int i = tid; i < RSZ; i += 256) hist[i] = 0;
        __syncthreads();
        const int4* d4 = (const int4*)(dst + c * CHSZ);
        for (int i = tid; i < CHSZ / 4; i += 256) {
            const int4 v = d4[i];
            int b;
            b = v.x - nb; if ((unsigned)b < (unsigned)RSZ) atomicAdd(&hist[b], 1);
            b = v.y - nb; if ((unsigned)b < (unsigned)RSZ) atomicAdd(&hist[b], 1);
            b = v.z - nb; if ((unsigned)b < (unsigned)RSZ) atomicAdd(&hist[b], 1);
            b = v.w - nb; if ((unsigned)b < (unsigned)RSZ) atomicAdd(&hist[b], 1);
        }
        __syncthreads();
        for (int i = tid; i < RSZ; i += 256)
            part[(size_t)c * NP + nb + i] = hist[i];
    } else {
        const int g = (bid - 128) * 256 + tid;
        if (g < 4096) {
            const int lane = g & 63;
            const int kq = (g >> 6) & 3;
            const int nt = g >> 8;           // 0..15
            const int cc = nt * 16 + (lane & 15);
            const int kbase = kq * 32 + (lane >> 4) * 8;
            const float* Wsel = (cc < 128) ? (Wg + cc) : (Ws + cc - 128);
            unsigned int pk[4];
#pragma unroll
            for (int p = 0; p < 4; p++) {
                const float v0 = Wsel[(size_t)(kbase + 2 * p) * HC];
                const float v1 = Wsel[(size_t)(kbase + 2 * p + 1) * HC];
                pk[p] = f2bf(v0) | (f2bf(v1) << 16);
            }
            *(uint4*)(Bfrag + (size_t)g * 8) = make_uint4(pk[0], pk[1], pk[2], pk[3]);
        }
    }
}

// ---------------------------------------------------------------------------
// K_scanA (merge fused): per node, chunk-exclusive-prefix part_t in place
// (16 coalesced passes), counts[n]=total; block-exclusive-scan of (counts+1)
// -> row_start; RAW block sums -> bsum. Multi-block (single-block = R5
// regression).
// ---------------------------------------------------------------------------
__global__ __launch_bounds__(256) void k_scanA(
    int* __restrict__ part, int* __restrict__ counts,
    int* __restrict__ row_start, int* __restrict__ bsum)
{
    __shared__ int s[256];
    const int tid = threadIdx.x;
    const int base = blockIdx.x * 1024 + tid * 4;
    int v[4]; int t = 0;
#pragma unroll
    for (int j = 0; j < 4; j++) {
        const int idx = base + j;
        if (idx < N_NODES) {
            int run = 0;
#pragma unroll
            for (int c = 0; c < 16; c++) {
                int* p = part + (size_t)c * NP + idx;
                const int q = *p;
                *p = run;
                run += q;
            }
            counts[idx] = run;
            v[j] = run + 1;                  // +1 = self-loop
        } else v[j] = 0;
        t += v[j];
    }
    s[tid] = t;
    __syncthreads();
    for (int off = 1; off < 256; off <<= 1) {
        int add = (tid >= off) ? s[tid - off] : 0;
        __syncthreads();
        s[tid] += add;
        __syncthreads();
    }
    int excl = s[tid] - t;
#pragma unroll
    for (int j = 0; j < 4; j++) {
        const int idx = base + j;
        if (idx < N_NODES) row_start[idx] = excl;
        excl += v[j];
    }
    if (tid == 255) bsum[blockIdx.x] = s[255];
}

// ---------------------------------------------------------------------------
// K_scanC (scanB folded in): each block redundantly wave-scans the 49 raw
// block sums to get its own offset, finalizes row_start, and writes each
// node's self-loop into its LAST csr slot (rs+counts[i]).
// ---------------------------------------------------------------------------
__global__ __launch_bounds__(256) void k_scanC(
    int* __restrict__ row_start, const int* __restrict__ bsum,
    const int* __restrict__ counts, int* __restrict__ csr)
{
    __shared__ int soff;
    const int tid = threadIdx.x;
    if (tid < 64) {
        const int tgt = blockIdx.x >> 2;      // scanA block covering this range
        int v = (tid < 49 && tid < tgt) ? bsum[tid] : 0;
#pragma unroll
        for (int off = 1; off < 64; off <<= 1) v += __shfl_xor(v, off);
        if (tid == 0) soff = v;
    }
    __syncthreads();
    const int i = blockIdx.x * 256 + tid;
    if (i < N_NODES) {
        const int rs = row_start[i] + soff;
        row_start[i] = rs;
        csr[rs + counts[i]] = i;
    }
}

// ---------------------------------------------------------------------------
// K_lf: fused linear(MFMA) + deterministic CSR fill (R7-proven layout: fill
// at bid<256, pos<8 so bid%8 == r — XCD pin; breaking it cost +40us in R8).
// Linear epilogue: h col-pairs staged to LDS [64][68] (16B-aligned rows),
// then one merged pass does coalesced uint4 h-stores AND per-(node,head)
// attention dots — replaces the old 512-shuffle + scalar-store epilogue.
// ---------------------------------------------------------------------------
__global__ __launch_bounds__(256) void k_lf(
    const float* __restrict__ x,
    const unsigned short* __restrict__ Bfrag,
    const float* __restrict__ att_s,
    const float* __restrict__ att_d,
    const float* __restrict__ bias,
    unsigned short* __restrict__ h_bf, unsigned int* __restrict__ z0b,
    float* __restrict__ a_src, float* __restrict__ a_dst,
    const int* __restrict__ src, const int* __restrict__ dst,
    const int* __restrict__ row_start, const int* __restrict__ part,
    int* __restrict__ csr)
{
    __shared__ __align__(16) int smem[RSZ];   // fill: cursors; linear: sA/hls
    const int bid = blockIdx.x;
    const int tid = threadIdx.x;
    int lin = -1, r = 0, c = 0;
    if (bid < 256) {
        const int g = bid >> 4, pos = bid & 15;
        if (pos < 8) { r = pos; c = g; }           // bid%8 == r  (XCD pin)
        else lin = g * 8 + (pos - 8);
    } else {
        lin = 128 + (bid - 256);
    }

    if (lin < 0) {
        // ---------------- CSR fill ----------------
        const int nb = r * RSZ;
        for (int b = tid; b < RSZ; b += 256)
            smem[b] = row_start[nb + b] + part[(size_t)c * NP + nb + b];
        __syncthreads();
        const int4* d4 = (const int4*)(dst + c * CHSZ);
        const int4* s4 = (const int4*)(src + c * CHSZ);
        for (int i = tid; i < CHSZ / 4; i += 256) {
            const int4 dv = d4[i];
            const int4 sv = s4[i];
            int b;
            b = dv.x - nb; if ((unsigned)b < (unsigned)RSZ) csr[atomicAdd(&smem[b], 1)] = sv.x;
            b = dv.y - nb; if ((unsigned)b < (unsigned)RSZ) csr[atomicAdd(&smem[b], 1)] = sv.y;
            b = dv.z - nb; if ((unsigned)b < (unsigned)RSZ) csr[atomicAdd(&smem[b], 1)] = sv.z;
            b = dv.w - nb; if ((unsigned)b < (unsigned)RSZ) csr[atomicAdd(&smem[b], 1)] = sv.w;
        }
        return;
    }

    // ---------------- linear (MFMA) ----------------
    unsigned short* sA = (unsigned short*)smem;   // [mt*4+kq][lane][j] 16 KB
    const int lane = tid & 63;
    const int w = tid >> 6;
    const int nbase = lin * 64;

    // stage A: x[64 nodes][128 k] -> bf16 fragment-major
#pragma unroll
    for (int it = 0; it < 4; it++) {
        const int p = it * 256 + tid;
        const int node = p >> 4;        // 0..63
        const int kg = p & 15;          // k-group of 8
        const int gn = nbase + node;
        float v[8];
        if (gn < N_NODES) {
            float4 u0 = *(const float4*)(x + (size_t)gn * F_IN + kg * 8);
            float4 u1 = *(const float4*)(x + (size_t)gn * F_IN + kg * 8 + 4);
            v[0] = u0.x; v[1] = u0.y; v[2] = u0.z; v[3] = u0.w;
            v[4] = u1.x; v[5] = u1.y; v[6] = u1.z; v[7] = u1.w;
        } else {
#pragma unroll
            for (int j = 0; j < 8; j++) v[j] = 0.f;
        }
        const int mt = node >> 4, lm = node & 15;
        const int kq = kg >> 2, quad = kg & 3;
        uint4 pk;
        pk.x = f2bf(v[0]) | (f2bf(v[1]) << 16);
        pk.y = f2bf(v[2]) | (f2bf(v[3]) << 16);
        pk.z = f2bf(v[4]) | (f2bf(v[5]) << 16);
        pk.w = f2bf(v[6]) | (f2bf(v[7]) << 16);
        *(uint4*)(sA + ((size_t)((mt * 4 + kq) * 64 + quad * 16 + lm)) * 8) = pk;
    }
    __syncthreads();

    const bf16x8* Bf = (const bf16x8*)Bfrag;
    f32x4 acc[4][4];
#pragma unroll
    for (int mt = 0; mt < 4; mt++)
#pragma unroll
        for (int nt = 0; nt < 4; nt++)
            acc[mt][nt] = (f32x4){0.f, 0.f, 0.f, 0.f};

#pragma unroll
    for (int kq = 0; kq < 4; kq++) {
        bf16x8 aF[4], bF[4];
#pragma unroll
        for (int nt = 0; nt < 4; nt++)
            bF[nt] = Bf[(size_t)(((w * 4 + nt) * 4 + kq) * 64 + lane)];
#pragma unroll
        for (int mt = 0; mt < 4; mt++)
            aF[mt] = *(const bf16x8*)(sA + ((size_t)((mt * 4 + kq) * 64 + lane)) * 8);
#pragma unroll
        for (int mt = 0; mt < 4; mt++)
#pragma unroll
            for (int nt = 0; nt < 4; nt++)
                acc[mt][nt] = __builtin_amdgcn_mfma_f32_16x16x32_bf16(
                    aF[mt], bF[nt], acc[mt][nt], 0, 0, 0);
    }

    __syncthreads();   // all waves done reading sA before hls overwrite

    // ---- epilogue phase 1: D[row=(lane>>4)*4+rr][col=lane&15] ----
    const int row4 = (lane >> 4) * 4;
    const int cl = lane & 15;
    unsigned int* hls = (unsigned int*)smem;   // [64][68] col-pair layout

    if (w < 2) {
        // pack h col-pairs into LDS
#pragma unroll
        for (int mt = 0; mt < 4; mt++) {
#pragma unroll
            for (int nt = 0; nt < 4; nt++) {
                const int cc = w * 64 + nt * 16 + cl;   // 0..127
                f32x4 d = acc[mt][nt];
#pragma unroll
                for (int rr = 0; rr < 4; rr++) {
                    const float oth = __shfl_xor(d[rr], 1);
                    if ((cl & 1) == 0) {
                        const int nl = mt * 16 + row4 + rr;
                        hls[nl * 68 + (cc >> 1)] = f2bf(d[rr]) | (f2bf(oth) << 16);
                    }
                }
            }
        }
    } else {
        // z0b: pack pairs + direct global store
#pragma unroll
        for (int mt = 0; mt < 4; mt++) {
#pragma unroll
            for (int nt = 0; nt < 4; nt++) {
                const int cz = (w - 2) * 64 + nt * 16 + cl;   // 0..127
                f32x4 d = acc[mt][nt];
                const float bv = bias[cz];
#pragma unroll
                for (int rr = 0; rr < 4; rr++) {
                    const int gn = nbase + mt * 16 + row4 + rr;
                    const float val = 0.1f * d[rr] + bv;
                    const float oth = __shfl_xor(val, 1);
                    if ((cl & 1) == 0 && gn < N_NODES)
                        z0b[(size_t)gn * 64 + (cz >> 1)] = f2bf(val) | (f2bf(oth) << 16);
                }
            }
        }
    }
    __syncthreads();

    // ---- epilogue phase 2: merged h-store + attention dots ----
    // thread t: row = t>>2, quad q = t&3 -> cols q*32..q*32+31 = heads 2q,2q+1
    {
        const int row = tid >> 2, q = tid & 3;
        const int gn = nbase + row;
        if (gn < N_NODES) {
            const unsigned int* hr = hls + row * 68 + q * 16;
            uint4 v0 = *(const uint4*)(hr);
            uint4 v1 = *(const uint4*)(hr + 4);
            uint4 v2 = *(const uint4*)(hr + 8);
            uint4 v3 = *(const uint4*)(hr + 12);
            uint4* hout = (uint4*)((unsigned int*)h_bf + (size_t)gn * 64 + q * 16);
            hout[0] = v0; hout[1] = v1; hout[2] = v2; hout[3] = v3;

            const unsigned int u[16] = {v0.x, v0.y, v0.z, v0.w,
                                        v1.x, v1.y, v1.z, v1.w,
                                        v2.x, v2.y, v2.z, v2.w,
                                        v3.x, v3.y, v3.z, v3.w};
            const int c0 = q * 32;
            const float4* as4 = (const float4*)(att_s + c0);   // 8 float4
            const float4* ad4 = (const float4*)(att_d + c0);
            float ds0 = 0.f, dd0 = 0.f, ds1 = 0.f, dd1 = 0.f;
#pragma unroll
            for (int j = 0; j < 4; j++) {
                // head 2q: uints 2j, 2j+1  <->  as4[j]
                const float4 sa = as4[j], da = ad4[j];
                float l0 = bf2f(u[2 * j] & 0xffffu),     h0v = bf2f(u[2 * j] >> 16);
                float l1 = bf2f(u[2 * j + 1] & 0xffffu), h1v = bf2f(u[2 * j + 1] >> 16);
                ds0 += l0 * sa.x + h0v * sa.y + l1 * sa.z + h1v * sa.w;
                dd0 += l0 * da.x + h0v * da.y + l1 * da.z + h1v * da.w;
                // head 2q+1: uints 8+2j, 8+2j+1  <->  as4[4+j]
                const float4 sb = as4[4 + j], db = ad4[4 + j];
                float l2 = bf2f(u[8 + 2 * j] & 0xffffu),     h2v = bf2f(u[8 + 2 * j] >> 16);
                float l3 = bf2f(u[8 + 2 * j + 1] & 0xffffu), h3v = bf2f(u[8 + 2 * j + 1] >> 16);
                ds1 += l2 * sb.x + h2v * sb.y + l3 * sb.z + h3v * sb.w;
                dd1 += l2 * db.x + h2v * db.y + l3 * db.z + h3v * db.w;
            }
            const int hh = 2 * q;
            a_src[gn * 8 + hh] = ds0;     a_src[gn * 8 + hh + 1] = ds1;
            a_dst[gn * 8 + hh] = dd0;     a_dst[gn * 8 + hh + 1] = dd1;
        }
    }
}

// ---------------------------------------------------------------------------
// K_agg: per-node aggregation + skip + LN + ELU.
// ONE node per 64-lane wave: rs/cnt via readfirstlane -> csr loads are
// wave-uniform scalar loads; h gather coalesced 256 B/row; batch-8 gathers;
// tail edges weight-masked (clamped index). cnt = counts[n]+1 (self-loop =
// last slot). Softmax max-subtraction cancels in (sum w*h)/(sum w).
// ---------------------------------------------------------------------------
__global__ __launch_bounds__(256) void k_agg(
    const unsigned int* __restrict__ h32,   // bf16 pairs, [N][64] uints
    const unsigned int* __restrict__ z0b,   // bf16 pairs, [N][64] uints
    const float* __restrict__ a_src, const float* __restrict__ a_dst,
    const int* __restrict__ row_start, const int* __restrict__ counts,
    const int* __restrict__ csr,
    const float* __restrict__ gamma, const float* __restrict__ beta,
    float* __restrict__ out)
{
    const int tid = threadIdx.x;
    const int lane = tid & 63;
    const int n = blockIdx.x * 4 + (tid >> 6);
    const int head = lane >> 3;              // cols 2*lane, 2*lane+1

    const float adn = a_dst[n * 8 + head];
    const int rs  = __builtin_amdgcn_readfirstlane(row_start[n]);
    const int cnt = __builtin_amdgcn_readfirstlane(counts[n]) + 1;

    float d_acc = 0.f, a0 = 0.f, a1 = 0.f;
    for (int i = 0; i < cnt; i += 8) {
        int s[8]; float ae[8], mk[8]; unsigned int hp[8];
#pragma unroll
        for (int j = 0; j < 8; j++) {
            const int e = i + j;
            const int ec = (e < cnt) ? e : (cnt - 1);
            mk[j] = (e < cnt) ? 1.f : 0.f;
            s[j] = csr[rs + ec];             // scalar (wave-uniform) load
        }
#pragma unroll
        for (int j = 0; j < 8; j++) ae[j] = a_src[s[j] * 8 + head];
#pragma unroll
        for (int j = 0; j < 8; j++) hp[j] = h32[(size_t)s[j] * 64 + lane];
#pragma unroll
        for (int j = 0; j < 8; j++) {
            float e = ae[j] + adn;
            e = (e > 0.f) ? e : 0.2f * e;    // leaky_relu(0.2)
            const float wgt = __expf(e) * mk[j];
            d_acc += wgt;
            a0 += wgt * bf2f(hp[j] & 0xffffu);
            a1 += wgt * bf2f(hp[j] >> 16);
        }
    }
    const float inv = 1.0f / d_acc;
    const unsigned int zp = z0b[(size_t)n * 64 + lane];
    float y0 = a0 * inv + bf2f(zp & 0xffffu);
    float y1 = a1 * inv + bf2f(zp >> 16);

    // LayerNorm over 128 cols (full-wave reduce)
    float ss = y0 + y1;
#pragma unroll
    for (int off = 1; off < 64; off <<= 1) ss += __shfl_xor(ss, off);
    const float mu = ss * (1.0f / 128.0f);
    const float d0 = y0 - mu, d1 = y1 - mu;
    float vs = d0 * d0 + d1 * d1;
#pragma unroll
    for (int off = 1; off < 64; off <<= 1) vs += __shfl_xor(vs, off);
    const float rstd = rsqrtf(vs * (1.0f / 128.0f) + 1e-5f);

    const float2 gv = *(const float2*)(gamma + lane * 2);
    const float2 bv = *(const float2*)(beta + lane * 2);
    float o0 = d0 * rstd * gv.x + bv.x;
    float o1 = d1 * rstd * gv.y + bv.y;
    o0 = (o0 > 0.f) ? o0 : (__expf(o0) - 1.0f);   // ELU
    o1 = (o1 > 0.f) ? o1 : (__expf(o1) - 1.0f);

    *(float2*)(out + (size_t)n * HC + lane * 2) = make_float2(o0, o1);
}

// ---------------------------------------------------------------------------
extern "C" void kernel_launch(void* const* d_in, const int* in_sizes, int n_in,
                              void* d_out, int out_size, void* d_ws, size_t ws_size,
                              hipStream_t stream) {
    const float* x   = (const float*)d_in[0];
    const int*   ei  = (const int*)d_in[1];
    const float* Wg  = (const float*)d_in[2];
    const float* as_ = (const float*)d_in[3];
    const float* ad_ = (const float*)d_in[4];
    const float* bg  = (const float*)d_in[5];
    const float* Wsk = (const float*)d_in[6];
    const float* gm  = (const float*)d_in[7];
    const float* bt  = (const float*)d_in[8];
    float* out = (float*)d_out;

    // workspace layout (bytes), ~35.9 MB total
    char* wsb = (char*)d_ws;
    unsigned short* h_bf  = (unsigned short*)wsb;              // [N][128] bf16
    unsigned int*   z0b   = (unsigned int*)(wsb + 12800000);   // [N][64] bf16x2
    float*          a_src = (float*)(wsb + 25600000);          // [N][8]
    float*          a_dst = (float*)(wsb + 27200000);          // [N][8]
    unsigned short* Bfrag = (unsigned short*)(wsb + 28800000); // 64 KB
    int*   counts = (int*)(wsb + 28865536);                    // 50048
    int*   row_st = (int*)(wsb + 29065728);                    // 50048
    int*   bsum   = (int*)(wsb + 29265920);                    // 256
    int*   csr    = (int*)(wsb + 29266944);                    // 850000
    int*   part   = (int*)(wsb + 32666944);                    // 16*NP

    const int* src = ei;
    const int* dst = ei + N_EDGES;

    k_hist <<<144, 256, 0, stream>>>(dst, Wg, Wsk, Bfrag, part);
    k_scanA<<<49, 256, 0, stream>>>(part, counts, row_st, bsum);
    k_scanC<<<196, 256, 0, stream>>>(row_st, bsum, counts, csr);
    k_lf   <<<910, 256, 0, stream>>>(x, Bfrag, as_, ad_, bg, h_bf, z0b,
                                     a_src, a_dst, src, dst, row_st, part, csr);
    k_agg  <<<N_NODES / 4, 256, 0, stream>>>((const unsigned int*)h_bf, z0b,
                                             a_src, a_dst, row_st, counts, csr,
                                             gm, bt, out);
}

// Round 11
// 209.060 us; speedup vs baseline: 1.0192x; 1.0192x over previous
//
#include <hip/hip_runtime.h>
#include <hip/hip_bf16.h>

#define N_NODES 50000
#define N_EDGES 800000
#define F_IN    128
#define HC      128      // H*C
#define NR      8        // node ranges (XCD-pinned fill: bid%8 == r)
#define RSZ     6250     // nodes per range
#define NCH     32       // edge chunks (halved serial loops vs NCH=16)
#define CHSZ    25000    // edges per chunk
#define NP      50048    // padded node stride for part_t[c][n]

typedef __attribute__((ext_vector_type(8))) short bf16x8;
typedef __attribute__((ext_vector_type(4))) float f32x4;

__device__ __forceinline__ float bf2f(unsigned int u16) {
    return __uint_as_float(u16 << 16);
}
__device__ __forceinline__ unsigned int f2bf(float f) {
    unsigned int u = __float_as_uint(f);
    return (u + 0x7fffu + ((u >> 16) & 1u)) >> 16;   // RNE
}

// ---------------------------------------------------------------------------
// Shared linear (MFMA) block body: 64 nodes, h_bf16=x@Wg, z0b=bias+0.1*x@Ws,
// a_src/a_dst attention dots. smem must be >= 6250 ints (sA 16KB / hls 17KB).
// ---------------------------------------------------------------------------
__device__ __forceinline__ void linear_block(
    int lin, int tid, int* smem,
    const float* __restrict__ x, const unsigned short* __restrict__ Bfrag,
    const float* __restrict__ att_s, const float* __restrict__ att_d,
    const float* __restrict__ bias,
    unsigned short* __restrict__ h_bf, unsigned int* __restrict__ z0b,
    float* __restrict__ a_src, float* __restrict__ a_dst)
{
    unsigned short* sA = (unsigned short*)smem;   // [mt*4+kq][lane][j] 16 KB
    const int lane = tid & 63;
    const int w = tid >> 6;
    const int nbase = lin * 64;

    // stage A: x[64 nodes][128 k] -> bf16 fragment-major
#pragma unroll
    for (int it = 0; it < 4; it++) {
        const int p = it * 256 + tid;
        const int node = p >> 4;        // 0..63
        const int kg = p & 15;          // k-group of 8
        const int gn = nbase + node;
        float v[8];
        if (gn < N_NODES) {
            float4 u0 = *(const float4*)(x + (size_t)gn * F_IN + kg * 8);
            float4 u1 = *(const float4*)(x + (size_t)gn * F_IN + kg * 8 + 4);
            v[0] = u0.x; v[1] = u0.y; v[2] = u0.z; v[3] = u0.w;
            v[4] = u1.x; v[5] = u1.y; v[6] = u1.z; v[7] = u1.w;
        } else {
#pragma unroll
            for (int j = 0; j < 8; j++) v[j] = 0.f;
        }
        const int mt = node >> 4, lm = node & 15;
        const int kq = kg >> 2, quad = kg & 3;
        uint4 pk;
        pk.x = f2bf(v[0]) | (f2bf(v[1]) << 16);
        pk.y = f2bf(v[2]) | (f2bf(v[3]) << 16);
        pk.z = f2bf(v[4]) | (f2bf(v[5]) << 16);
        pk.w = f2bf(v[6]) | (f2bf(v[7]) << 16);
        *(uint4*)(sA + ((size_t)((mt * 4 + kq) * 64 + quad * 16 + lm)) * 8) = pk;
    }
    __syncthreads();

    const bf16x8* Bf = (const bf16x8*)Bfrag;
    f32x4 acc[4][4];
#pragma unroll
    for (int mt = 0; mt < 4; mt++)
#pragma unroll
        for (int nt = 0; nt < 4; nt++)
            acc[mt][nt] = (f32x4){0.f, 0.f, 0.f, 0.f};

#pragma unroll
    for (int kq = 0; kq < 4; kq++) {
        bf16x8 aF[4], bF[4];
#pragma unroll
        for (int nt = 0; nt < 4; nt++)
            bF[nt] = Bf[(size_t)(((w * 4 + nt) * 4 + kq) * 64 + lane)];
#pragma unroll
        for (int mt = 0; mt < 4; mt++)
            aF[mt] = *(const bf16x8*)(sA + ((size_t)((mt * 4 + kq) * 64 + lane)) * 8);
#pragma unroll
        for (int mt = 0; mt < 4; mt++)
#pragma unroll
            for (int nt = 0; nt < 4; nt++)
                acc[mt][nt] = __builtin_amdgcn_mfma_f32_16x16x32_bf16(
                    aF[mt], bF[nt], acc[mt][nt], 0, 0, 0);
    }

    __syncthreads();   // done reading sA before hls overwrite

    // epilogue phase 1: D[row=(lane>>4)*4+rr][col=lane&15]
    const int row4 = (lane >> 4) * 4;
    const int cl = lane & 15;
    unsigned int* hls = (unsigned int*)smem;   // [64][68] col-pair layout

    if (w < 2) {
#pragma unroll
        for (int mt = 0; mt < 4; mt++) {
#pragma unroll
            for (int nt = 0; nt < 4; nt++) {
                const int cc = w * 64 + nt * 16 + cl;   // 0..127
                f32x4 d = acc[mt][nt];
#pragma unroll
                for (int rr = 0; rr < 4; rr++) {
                    const float oth = __shfl_xor(d[rr], 1);
                    if ((cl & 1) == 0) {
                        const int nl = mt * 16 + row4 + rr;
                        hls[nl * 68 + (cc >> 1)] = f2bf(d[rr]) | (f2bf(oth) << 16);
                    }
                }
            }
        }
    } else {
#pragma unroll
        for (int mt = 0; mt < 4; mt++) {
#pragma unroll
            for (int nt = 0; nt < 4; nt++) {
                const int cz = (w - 2) * 64 + nt * 16 + cl;   // 0..127
                f32x4 d = acc[mt][nt];
                const float bv = bias[cz];
#pragma unroll
                for (int rr = 0; rr < 4; rr++) {
                    const int gn = nbase + mt * 16 + row4 + rr;
                    const float val = 0.1f * d[rr] + bv;
                    const float oth = __shfl_xor(val, 1);
                    if ((cl & 1) == 0 && gn < N_NODES)
                        z0b[(size_t)gn * 64 + (cz >> 1)] = f2bf(val) | (f2bf(oth) << 16);
                }
            }
        }
    }
    __syncthreads();

    // epilogue phase 2: merged coalesced h-store + attention dots
    {
        const int row = tid >> 2, q = tid & 3;
        const int gn = nbase + row;
        if (gn < N_NODES) {
            const unsigned int* hr = hls + row * 68 + q * 16;
            uint4 v0 = *(const uint4*)(hr);
            uint4 v1 = *(const uint4*)(hr + 4);
            uint4 v2 = *(const uint4*)(hr + 8);
            uint4 v3 = *(const uint4*)(hr + 12);
            uint4* hout = (uint4*)((unsigned int*)h_bf + (size_t)gn * 64 + q * 16);
            hout[0] = v0; hout[1] = v1; hout[2] = v2; hout[3] = v3;

            const unsigned int u[16] = {v0.x, v0.y, v0.z, v0.w,
                                        v1.x, v1.y, v1.z, v1.w,
                                        v2.x, v2.y, v2.z, v2.w,
                                        v3.x, v3.y, v3.z, v3.w};
            const int c0 = q * 32;
            const float4* as4 = (const float4*)(att_s + c0);
            const float4* ad4 = (const float4*)(att_d + c0);
            float ds0 = 0.f, dd0 = 0.f, ds1 = 0.f, dd1 = 0.f;
#pragma unroll
            for (int j = 0; j < 4; j++) {
                const float4 sa = as4[j], da = ad4[j];
                float l0 = bf2f(u[2 * j] & 0xffffu),     h0v = bf2f(u[2 * j] >> 16);
                float l1 = bf2f(u[2 * j + 1] & 0xffffu), h1v = bf2f(u[2 * j + 1] >> 16);
                ds0 += l0 * sa.x + h0v * sa.y + l1 * sa.z + h1v * sa.w;
                dd0 += l0 * da.x + h0v * da.y + l1 * da.z + h1v * da.w;
                const float4 sb = as4[4 + j], db = ad4[4 + j];
                float l2 = bf2f(u[8 + 2 * j] & 0xffffu),     h2v = bf2f(u[8 + 2 * j] >> 16);
                float l3 = bf2f(u[8 + 2 * j + 1] & 0xffffu), h3v = bf2f(u[8 + 2 * j + 1] >> 16);
                ds1 += l2 * sb.x + h2v * sb.y + l3 * sb.z + h3v * sb.w;
                dd1 += l2 * db.x + h2v * db.y + l3 * db.z + h3v * db.w;
            }
            const int hh = 2 * q;
            a_src[gn * 8 + hh] = ds0;     a_src[gn * 8 + hh + 1] = ds1;
            a_dst[gn * 8 + hh] = dd0;     a_dst[gn * 8 + hh + 1] = dd1;
        }
    }
}

// ---------------------------------------------------------------------------
// K_pack: 16 blocks — [Wg|Ws] -> Bfrag (MFMA-B fragment-major bf16). Runs
// FIRST so later dispatches can mix linear blocks without a pack race.
// ---------------------------------------------------------------------------
__global__ __launch_bounds__(256) void k_pack(
    const float* __restrict__ Wg, const float* __restrict__ Ws,
    unsigned short* __restrict__ Bfrag)
{
    const int g = blockIdx.x * 256 + threadIdx.x;
    if (g < 4096) {
        const int lane = g & 63;
        const int kq = (g >> 6) & 3;
        const int nt = g >> 8;           // 0..15
        const int cc = nt * 16 + (lane & 15);
        const int kbase = kq * 32 + (lane >> 4) * 8;
        const float* Wsel = (cc < 128) ? (Wg + cc) : (Ws + cc - 128);
        unsigned int pk[4];
#pragma unroll
        for (int p = 0; p < 4; p++) {
            const float v0 = Wsel[(size_t)(kbase + 2 * p) * HC];
            const float v1 = Wsel[(size_t)(kbase + 2 * p + 1) * HC];
            pk[p] = f2bf(v0) | (f2bf(v1) << 16);
        }
        *(uint4*)(Bfrag + (size_t)g * 8) = make_uint4(pk[0], pk[1], pk[2], pk[3]);
    }
}

// ---------------------------------------------------------------------------
// K_hl: hist (256 blocks: r=bid&7, c=bid>>3, chunk of 25K edges -> LDS
// sub-histogram -> coalesced part_t[c][n]) + linear blocks 0..259.
// ---------------------------------------------------------------------------
__global__ __launch_bounds__(256) void k_hl(
    const int* __restrict__ dst, int* __restrict__ part,
    const float* __restrict__ x, const unsigned short* __restrict__ Bfrag,
    const float* __restrict__ att_s, const float* __restrict__ att_d,
    const float* __restrict__ bias,
    unsigned short* __restrict__ h_bf, unsigned int* __restrict__ z0b,
    float* __restrict__ a_src, float* __restrict__ a_dst)
{
    __shared__ __align__(16) int smem[RSZ];
    const int bid = blockIdx.x;
    const int tid = threadIdx.x;
    if (bid < 256) {
        // ---------------- histogram ----------------
        const int r = bid & 7, c = bid >> 3;
        const int nb = r * RSZ;
        for (int i = tid; i < RSZ; i += 256) smem[i] = 0;
        __syncthreads();
        const int4* d4 = (const int4*)(dst + c * CHSZ);
        for (int i = tid; i < CHSZ / 4; i += 256) {
            const int4 v = d4[i];
            int b;
            b = v.x - nb; if ((unsigned)b < (unsigned)RSZ) atomicAdd(&smem[b], 1);
            b = v.y - nb; if ((unsigned)b < (unsigned)RSZ) atomicAdd(&smem[b], 1);
            b = v.z - nb; if ((unsigned)b < (unsigned)RSZ) atomicAdd(&smem[b], 1);
            b = v.w - nb; if ((unsigned)b < (unsigned)RSZ) atomicAdd(&smem[b], 1);
        }
        __syncthreads();
        for (int i = tid; i < RSZ; i += 256)
            part[(size_t)c * NP + nb + i] = smem[i];
        return;
    }
    linear_block(bid - 256, tid, smem, x, Bfrag, att_s, att_d, bias,
                 h_bf, z0b, a_src, a_dst);
}

// ---------------------------------------------------------------------------
// K_sl: scanA (49 blocks: 32-chunk prefix of part_t per node, counts,
// block-exclusive scan of counts+1 -> row_start, raw sums -> bsum)
// + linear blocks 260..520.
// ---------------------------------------------------------------------------
__global__ __launch_bounds__(256) void k_sl(
    int* __restrict__ part, int* __restrict__ counts,
    int* __restrict__ row_start, int* __restrict__ bsum,
    const float* __restrict__ x, const unsigned short* __restrict__ Bfrag,
    const float* __restrict__ att_s, const float* __restrict__ att_d,
    const float* __restrict__ bias,
    unsigned short* __restrict__ h_bf, unsigned int* __restrict__ z0b,
    float* __restrict__ a_src, float* __restrict__ a_dst)
{
    __shared__ __align__(16) int smem[RSZ];
    const int bid = blockIdx.x;
    const int tid = threadIdx.x;
    if (bid < 49) {
        int* s = smem;   // 256 ints used
        const int base = bid * 1024 + tid * 4;
        int v[4]; int t = 0;
#pragma unroll
        for (int j = 0; j < 4; j++) {
            const int idx = base + j;
            if (idx < N_NODES) {
                int run = 0;
#pragma unroll
                for (int c = 0; c < NCH; c++) {
                    int* p = part + (size_t)c * NP + idx;
                    const int q = *p;
                    *p = run;
                    run += q;
                }
                counts[idx] = run;
                v[j] = run + 1;              // +1 = self-loop
            } else v[j] = 0;
            t += v[j];
        }
        s[tid] = t;
        __syncthreads();
        for (int off = 1; off < 256; off <<= 1) {
            int add = (tid >= off) ? s[tid - off] : 0;
            __syncthreads();
            s[tid] += add;
            __syncthreads();
        }
        int excl = s[tid] - t;
#pragma unroll
        for (int j = 0; j < 4; j++) {
            const int idx = base + j;
            if (idx < N_NODES) row_start[idx] = excl;
            excl += v[j];
        }
        if (tid == 255) bsum[bid] = s[255];
        return;
    }
    linear_block(260 + (bid - 49), tid, smem, x, Bfrag, att_s, att_d, bias,
                 h_bf, z0b, a_src, a_dst);
}

// ---------------------------------------------------------------------------
// K_scanC: each block wave-scans the 49 raw block sums for its offset,
// finalizes row_start, writes each node's self-loop into its LAST csr slot.
// ---------------------------------------------------------------------------
__global__ __launch_bounds__(256) void k_scanC(
    int* __restrict__ row_start, const int* __restrict__ bsum,
    const int* __restrict__ counts, int* __restrict__ csr)
{
    __shared__ int soff;
    const int tid = threadIdx.x;
    if (tid < 64) {
        const int tgt = blockIdx.x >> 2;      // scanA block covering this range
        int v = (tid < 49 && tid < tgt) ? bsum[tid] : 0;
#pragma unroll
        for (int off = 1; off < 64; off <<= 1) v += __shfl_xor(v, off);
        if (tid == 0) soff = v;
    }
    __syncthreads();
    const int i = blockIdx.x * 256 + tid;
    if (i < N_NODES) {
        const int rs = row_start[i] + soff;
        row_start[i] = rs;
        csr[rs + counts[i]] = i;
    }
}

// ---------------------------------------------------------------------------
// K_lf: deterministic CSR fill (256 blocks at bid<512, pos<8: r=pos so
// bid%8==r — XCD pin, R8 lesson) + linear blocks 521..781. LDS cursors =
// row_start + part_t (coalesced); LDS-atomic rank -> scatter within range
// slice. No global atomics.
// ---------------------------------------------------------------------------
__global__ __launch_bounds__(256) void k_lf(
    const int* __restrict__ src, const int* __restrict__ dst,
    const int* __restrict__ row_start, const int* __restrict__ part,
    int* __restrict__ csr,
    const float* __restrict__ x, const unsigned short* __restrict__ Bfrag,
    const float* __restrict__ att_s, const float* __restrict__ att_d,
    const float* __restrict__ bias,
    unsigned short* __restrict__ h_bf, unsigned int* __restrict__ z0b,
    float* __restrict__ a_src, float* __restrict__ a_dst)
{
    __shared__ __align__(16) int smem[RSZ];
    const int bid = blockIdx.x;
    const int tid = threadIdx.x;
    int lin;
    if (bid < 512) {
        const int c = bid >> 4, pos = bid & 15;
        if (pos < 8) {
            // ---------------- CSR fill ----------------
            const int r = pos;                   // bid%8 == r (XCD pin)
            const int nb = r * RSZ;
            for (int b = tid; b < RSZ; b += 256)
                smem[b] = row_start[nb + b] + part[(size_t)c * NP + nb + b];
            __syncthreads();
            const int4* d4 = (const int4*)(dst + c * CHSZ);
            const int4* s4 = (const int4*)(src + c * CHSZ);
            for (int i = tid; i < CHSZ / 4; i += 256) {
                const int4 dv = d4[i];
                const int4 sv = s4[i];
                int b;
                b = dv.x - nb; if ((unsigned)b < (unsigned)RSZ) csr[atomicAdd(&smem[b], 1)] = sv.x;
                b = dv.y - nb; if ((unsigned)b < (unsigned)RSZ) csr[atomicAdd(&smem[b], 1)] = sv.y;
                b = dv.z - nb; if ((unsigned)b < (unsigned)RSZ) csr[atomicAdd(&smem[b], 1)] = sv.z;
                b = dv.w - nb; if ((unsigned)b < (unsigned)RSZ) csr[atomicAdd(&smem[b], 1)] = sv.w;
            }
            return;
        }
        lin = 521 + c * 8 + (pos - 8);           // 521..776
    } else {
        lin = 777 + (bid - 512);                 // 777..781
    }
    linear_block(lin, tid, smem, x, Bfrag, att_s, att_d, bias,
                 h_bf, z0b, a_src, a_dst);
}

// ---------------------------------------------------------------------------
// K_agg: per-node aggregation + skip + LN + ELU. One node per 64-lane wave;
// csr reads wave-uniform (scalar); batch-8 gathers; tail weight-masked.
// cnt = counts[n]+1 (self-loop = last slot). Softmax max-subtraction cancels
// in (sum w*h)/(sum w).
// ---------------------------------------------------------------------------
__global__ __launch_bounds__(256) void k_agg(
    const unsigned int* __restrict__ h32,   // bf16 pairs, [N][64] uints
    const unsigned int* __restrict__ z0b,   // bf16 pairs, [N][64] uints
    const float* __restrict__ a_src, const float* __restrict__ a_dst,
    const int* __restrict__ row_start, const int* __restrict__ counts,
    const int* __restrict__ csr,
    const float* __restrict__ gamma, const float* __restrict__ beta,
    float* __restrict__ out)
{
    const int tid = threadIdx.x;
    const int lane = tid & 63;
    const int n = blockIdx.x * 4 + (tid >> 6);
    const int head = lane >> 3;              // cols 2*lane, 2*lane+1

    const float adn = a_dst[n * 8 + head];
    const int rs  = __builtin_amdgcn_readfirstlane(row_start[n]);
    const int cnt = __builtin_amdgcn_readfirstlane(counts[n]) + 1;

    float d_acc = 0.f, a0 = 0.f, a1 = 0.f;
    for (int i = 0; i < cnt; i += 8) {
        int s[8]; float ae[8], mk[8]; unsigned int hp[8];
#pragma unroll
        for (int j = 0; j < 8; j++) {
            const int e = i + j;
            const int ec = (e < cnt) ? e : (cnt - 1);
            mk[j] = (e < cnt) ? 1.f : 0.f;
            s[j] = csr[rs + ec];             // wave-uniform scalar load
        }
#pragma unroll
        for (int j = 0; j < 8; j++) ae[j] = a_src[s[j] * 8 + head];
#pragma unroll
        for (int j = 0; j < 8; j++) hp[j] = h32[(size_t)s[j] * 64 + lane];
#pragma unroll
        for (int j = 0; j < 8; j++) {
            float e = ae[j] + adn;
            e = (e > 0.f) ? e : 0.2f * e;    // leaky_relu(0.2)
            const float wgt = __expf(e) * mk[j];
            d_acc += wgt;
            a0 += wgt * bf2f(hp[j] & 0xffffu);
            a1 += wgt * bf2f(hp[j] >> 16);
        }
    }
    const float inv = 1.0f / d_acc;
    const unsigned int zp = z0b[(size_t)n * 64 + lane];
    float y0 = a0 * inv + bf2f(zp & 0xffffu);
    float y1 = a1 * inv + bf2f(zp >> 16);

    // LayerNorm over 128 cols (full-wave reduce)
    float ss = y0 + y1;
#pragma unroll
    for (int off = 1; off < 64; off <<= 1) ss += __shfl_xor(ss, off);
    const float mu = ss * (1.0f / 128.0f);
    const float d0 = y0 - mu, d1 = y1 - mu;
    float vs = d0 * d0 + d1 * d1;
#pragma unroll
    for (int off = 1; off < 64; off <<= 1) vs += __shfl_xor(vs, off);
    const float rstd = rsqrtf(vs * (1.0f / 128.0f) + 1e-5f);

    const float2 gv = *(const float2*)(gamma + lane * 2);
    const float2 bv = *(const float2*)(beta + lane * 2);
    float o0 = d0 * rstd * gv.x + bv.x;
    float o1 = d1 * rstd * gv.y + bv.y;
    o0 = (o0 > 0.f) ? o0 : (__expf(o0) - 1.0f);   // ELU
    o1 = (o1 > 0.f) ? o1 : (__expf(o1) - 1.0f);

    *(float2*)(out + (size_t)n * HC + lane * 2) = make_float2(o0, o1);
}

// ---------------------------------------------------------------------------
extern "C" void kernel_launch(void* const* d_in, const int* in_sizes, int n_in,
                              void* d_out, int out_size, void* d_ws, size_t ws_size,
                              hipStream_t stream) {
    const float* x   = (const float*)d_in[0];
    const int*   ei  = (const int*)d_in[1];
    const float* Wg  = (const float*)d_in[2];
    const float* as_ = (const float*)d_in[3];
    const float* ad_ = (const float*)d_in[4];
    const float* bg  = (const float*)d_in[5];
    const float* Wsk = (const float*)d_in[6];
    const float* gm  = (const float*)d_in[7];
    const float* bt  = (const float*)d_in[8];
    float* out = (float*)d_out;

    // workspace layout (bytes), ~39.1 MB total
    char* wsb = (char*)d_ws;
    unsigned short* h_bf  = (unsigned short*)wsb;              // [N][128] bf16
    unsigned int*   z0b   = (unsigned int*)(wsb + 12800000);   // [N][64] bf16x2
    float*          a_src = (float*)(wsb + 25600000);          // [N][8]
    float*          a_dst = (float*)(wsb + 27200000);          // [N][8]
    unsigned short* Bfrag = (unsigned short*)(wsb + 28800000); // 64 KB
    int*   counts = (int*)(wsb + 28865536);                    // 50048
    int*   row_st = (int*)(wsb + 29065728);                    // 50048
    int*   bsum   = (int*)(wsb + 29265920);                    // 256
    int*   csr    = (int*)(wsb + 29266944);                    // 850000
    int*   part   = (int*)(wsb + 32666944);                    // 32*NP ints

    const int* src = ei;
    const int* dst = ei + N_EDGES;

    k_pack <<<16, 256, 0, stream>>>(Wg, Wsk, Bfrag);
    k_hl   <<<516, 256, 0, stream>>>(dst, part, x, Bfrag, as_, ad_, bg,
                                     h_bf, z0b, a_src, a_dst);
    k_sl   <<<310, 256, 0, stream>>>(part, counts, row_st, bsum,
                                     x, Bfrag, as_, ad_, bg,
                                     h_bf, z0b, a_src, a_dst);
    k_scanC<<<196, 256, 0, stream>>>(row_st, bsum, counts, csr);
    k_lf   <<<517, 256, 0, stream>>>(src, dst, row_st, part, csr,
                                     x, Bfrag, as_, ad_, bg,
                                     h_bf, z0b, a_src, a_dst);
    k_agg  <<<N_NODES / 4, 256, 0, stream>>>((const unsigned int*)h_bf, z0b,
                                             a_src, a_dst, row_st, counts, csr,
                                             gm, bt, out);
}